// Round 5
// baseline (161.430 us; speedup 1.0000x reference)
//
#include <hip/hip_runtime.h>
#include <stdint.h>

// CoEncoderDynamicAttention: B=2,S=2048,H=1024,NH=16,NKV=4,HD=64, out=(B,S,1)
// out[b,q] = sum_h (sum_k e_{hqk} * vproj[b,h,k]) / (sum_k e_{hqk})
// vproj = hs @ (wv folded with wo)  -> attn@V GEMM eliminated.
// Q' = hs@wq * (log2e/8)  -> weight = exp2(Q'.K).
// Mask folded as accumulator-init bias (0 / -30000) -> exp2 gives exact 0.

typedef __bf16 bf16x8 __attribute__((ext_vector_type(8)));
typedef float f32x4 __attribute__((ext_vector_type(4)));

__device__ inline unsigned short f2bf(float f) {
    unsigned int u = __builtin_bit_cast(unsigned int, f);
    u += 0x7fff + ((u >> 16) & 1);   // RNE
    return (unsigned short)(u >> 16);
}
__device__ inline bf16x8 ldfrag(const unsigned short* p) {
    uint4 v = *(const uint4*)p;
    return __builtin_bit_cast(bf16x8, v);
}
__device__ inline void gl2lds16(const unsigned short* g, unsigned short* l) {
    // 64 lanes x 16B: per-lane global addr, LDS dst = wave-uniform base + lane*16
    __builtin_amdgcn_global_load_lds(
        (const __attribute__((address_space(1))) void*)g,
        (__attribute__((address_space(3))) void*)l, 16, 0, 0);
}

#define SCALE_Q 0.18033688011112042f   // log2(e)/8

// ---------------- prep: hs->bf16; wT = [wq^T*s | wk^T | wvo^T | zeros] (1408x1024 bf16)
__global__ __launch_bounds__(256) void prep_kernel(
    const float* __restrict__ hs, const float* __restrict__ wq,
    const float* __restrict__ wk, const float* __restrict__ wv,
    const float* __restrict__ wo,
    unsigned short* __restrict__ hs_bf, unsigned short* __restrict__ wT)
{
    int bid = blockIdx.x, tid = threadIdx.x;
    if (bid < 4096) {
        int u = bid * 256 + tid;
        float4 v = ((const float4*)hs)[u];
        ushort4 o;
        o.x = f2bf(v.x); o.y = f2bf(v.y); o.z = f2bf(v.z); o.w = f2bf(v.w);
        ((ushort4*)hs_bf)[u] = o;
    } else if (bid < 4416) {
        __shared__ float tile[64 * 65];
        int t = bid - 4096;
        int ntile = t / 16, ctile = t % 16;
        int nb = ntile * 64, cb = ctile * 64;
        int tx = tid & 63, ty = tid >> 6;
        for (int i = 0; i < 16; i++) {
            int cl = i * 4 + ty;
            int n = nb + tx;
            float v = (n < 1024) ? wq[(cb + cl) * 1024 + n] * SCALE_Q
                                 : wk[(cb + cl) * 256 + (n - 1024)];
            tile[cl * 65 + tx] = v;
        }
        __syncthreads();
        for (int i = 0; i < 16; i++) {
            int nl = i * 4 + ty;
            wT[(nb + nl) * 1024 + cb + tx] = f2bf(tile[tx * 65 + nl]);
        }
    } else {
        int u = (bid - 4416) * 256 + tid;
        int n2 = u >> 10, c = u & 1023;
        if (n2 < 16) {
            int h = n2, kv = h >> 2;
            const float* wvr = wv + c * 256 + kv * 64;
            const float* wor = wo + h * 64;
            float s = 0.f;
            #pragma unroll 8
            for (int d = 0; d < 64; d++) s += wvr[d] * wor[d];
            wT[(1280 + n2) * 1024 + c] = f2bf(s);
        } else {
            wT[(1280 + n2) * 1024 + c] = 0;
        }
    }
}

// ---------------- gemm v2: 128(m=weight-col) x 64(r) tiles -> grid 11x64 = 704 blocks.
// D[n][r] = sum_c wT[n][c]*hs_bf[r][c]. n-tiles: 0..7 Q' bf16, 8..9 K bf16, 10 vproj f32.
__global__ __launch_bounds__(256) void gemm_kernel(
    const unsigned short* __restrict__ hs_bf, const unsigned short* __restrict__ wT,
    unsigned short* __restrict__ Qp, unsigned short* __restrict__ Kp,
    float* __restrict__ vproj)
{
    __shared__ __align__(16) unsigned short Al[128 * 32];
    __shared__ __align__(16) unsigned short Bl[64 * 32];
    int nt = blockIdx.x, rt = blockIdx.y;
    int tid = threadIdx.x;
    int lane = tid & 63, w = tid >> 6;
    int l15 = lane & 15, quad = lane >> 4;
    int wm = (w >> 1) * 64, wn = (w & 1) * 32;

    f32x4 acc[4][2];
    const f32x4 zero = {0.f, 0.f, 0.f, 0.f};
    for (int i = 0; i < 4; i++) for (int j = 0; j < 2; j++) acc[i][j] = zero;

    int arow = nt * 128, rrow = rt * 64;
    int scol = (lane & 3) * 8;
    // A: wave w stages rows w*32 .. w*32+31 (two 16-row insts)
    const unsigned short* ga = wT + (size_t)(arow + w * 32 + (lane >> 2)) * 1024 + scol;
    // B: wave w stages rows w*16 .. w*16+15 (one inst)
    const unsigned short* gb = hs_bf + (size_t)(rrow + w * 16 + (lane >> 2)) * 1024 + scol;
    unsigned short* la = Al + (w * 32) * 32;
    unsigned short* lb = Bl + (w * 16) * 32;

    for (int kk = 0; kk < 32; kk++) {
        gl2lds16(ga,             la);
        gl2lds16(ga + 16 * 1024, la + 16 * 32);
        gl2lds16(gb,             lb);
        ga += 32; gb += 32;
        __syncthreads();
        bf16x8 af[4], bfr[2];
        for (int i = 0; i < 4; i++)
            af[i]  = ldfrag(Al + (wm + i * 16 + l15) * 32 + quad * 8);
        for (int j = 0; j < 2; j++)
            bfr[j] = ldfrag(Bl + (wn + j * 16 + l15) * 32 + quad * 8);
        for (int i = 0; i < 4; i++)
            for (int j = 0; j < 2; j++)
                acc[i][j] = __builtin_amdgcn_mfma_f32_16x16x32_bf16(af[i], bfr[j], acc[i][j], 0, 0, 0);
        __syncthreads();
    }

    for (int i = 0; i < 4; i++) {
        for (int j = 0; j < 2; j++) {
            int nw = nt * 128 + wm + i * 16 + quad * 4;
            int r  = rt * 64 + wn + j * 16 + l15;
            if (nt < 8) {
                ushort4 o;
                o.x = f2bf(acc[i][j][0]); o.y = f2bf(acc[i][j][1]);
                o.z = f2bf(acc[i][j][2]); o.w = f2bf(acc[i][j][3]);
                *(ushort4*)(Qp + (size_t)r * 1024 + nw) = o;
            } else if (nt < 10) {
                ushort4 o;
                o.x = f2bf(acc[i][j][0]); o.y = f2bf(acc[i][j][1]);
                o.z = f2bf(acc[i][j][2]); o.w = f2bf(acc[i][j][3]);
                *(ushort4*)(Kp + (size_t)r * 256 + (nw - 1024)) = o;
            } else {
                for (int rg = 0; rg < 4; rg++) {
                    int h = nw + rg - 1280;
                    if (h < 16)
                        vproj[((size_t)(r >> 11) * 16 + h) * 2048 + (r & 2047)] = acc[i][j][rg];
                }
            }
        }
    }
}

// ---------------- attention v3: block = (b,kv,qtile64,ks512); wave w -> h = kv*4+w.
// Two 256-row K tiles per block; 4 independent q-chains per wave; mask as C-init bias.
__global__ __launch_bounds__(256) void attn_kernel(
    const unsigned short* __restrict__ Qp, const unsigned short* __restrict__ Kp,
    const float* __restrict__ vproj, const int* __restrict__ mask,
    float2* __restrict__ part)
{
    __shared__ __align__(16) unsigned short Kl[256 * 80];  // stride 80: measured 0 conflicts
    __shared__ __align__(16) float vpml[4 * 256];
    __shared__ __align__(16) float biasl[256];
    int qt = blockIdx.x;                       // 0..31
    int b = blockIdx.y >> 2, kv = blockIdx.y & 3;
    int ks = blockIdx.z;                       // 0..3 (512 k each)
    int tid = threadIdx.x, lane = tid & 63, w = tid >> 6;
    int l15 = lane & 15, quad = lane >> 4;
    int h = kv * 4 + w;
    int qrow0 = qt * 64;

    // Q fragments held across whole block: B-operand layout B[n=q (l15)][k=d]
    bf16x8 qf[4][2];
    for (int qs = 0; qs < 4; qs++) {
        const unsigned short* qp =
            Qp + (size_t)(b * 2048 + qrow0 + qs * 16 + l15) * 1024 + h * 64 + quad * 8;
        qf[qs][0] = ldfrag(qp);
        qf[qs][1] = ldfrag(qp + 32);
    }

    float num[4] = {0.f, 0.f, 0.f, 0.f}, den[4] = {0.f, 0.f, 0.f, 0.f};
    for (int kt = 0; kt < 2; kt++) {
        int k0 = ks * 512 + kt * 256;
        // stage K: 256 rows x 8 chunks of 8 shorts = 2048 units
        for (int it = 0; it < 8; it++) {
            int u = it * 256 + tid;
            int row = u >> 3, ch = u & 7;
            *(uint4*)(Kl + row * 80 + ch * 8) =
                *(const uint4*)(Kp + (size_t)(b * 2048 + k0 + row) * 256 + kv * 64 + ch * 8);
        }
        {   // vproj slice per h (4 h x 256 k)
            int h2 = tid >> 6, kk = (tid & 63) * 4;
            *(float4*)(vpml + h2 * 256 + kk) =
                *(const float4*)(vproj + ((size_t)b * 16 + kv * 4 + h2) * 2048 + k0 + kk);
        }
        if (tid < 64) {
            int4 mm = *(const int4*)(mask + b * 2048 + k0 + tid * 4);
            float4 bb;
            bb.x = mm.x ? 0.f : -30000.f;
            bb.y = mm.y ? 0.f : -30000.f;
            bb.z = mm.z ? 0.f : -30000.f;
            bb.w = mm.w ? 0.f : -30000.f;
            *(float4*)(biasl + tid * 4) = bb;
        }
        __syncthreads();

        for (int t8 = 0; t8 < 16; t8++) {
            const unsigned short* kb = Kl + (t8 * 16 + l15) * 80 + quad * 8;
            bf16x8 a0 = ldfrag(kb);           // A[m=k-row (l15)][k=d 0..31]
            bf16x8 a1 = ldfrag(kb + 32);      // d 32..63
            f32x4 vpm4 = *(const f32x4*)(vpml + w * 256 + t8 * 16 + quad * 4);
            f32x4 c4   = *(const f32x4*)(biasl + t8 * 16 + quad * 4);  // mask bias per k-row
            for (int qs = 0; qs < 4; qs++) {
                f32x4 d = __builtin_amdgcn_mfma_f32_16x16x32_bf16(a0, qf[qs][0], c4, 0, 0, 0);
                d = __builtin_amdgcn_mfma_f32_16x16x32_bf16(a1, qf[qs][1], d, 0, 0, 0);
                for (int r = 0; r < 4; r++) {
                    float e = __builtin_amdgcn_exp2f(d[r]);   // 0 for masked rows
                    num[qs] += e * vpm4[r];
                    den[qs] += e;
                }
            }
        }
        __syncthreads();   // protect restage of next tile
    }
    for (int qs = 0; qs < 4; qs++) {
        float n = num[qs], dd = den[qs];
        n += __shfl_xor(n, 16);  n += __shfl_xor(n, 32);
        dd += __shfl_xor(dd, 16); dd += __shfl_xor(dd, 32);
        if (quad == 0) {
            int q = qrow0 + qs * 16 + l15;
            part[((size_t)(b * 2048 + q) * 16 + h) * 4 + ks] = make_float2(n, dd);
        }
    }
}

// ---------------- combine: out[b,q] = sum_h (sum_ks num)/(sum_ks den); one wave per (b,q)
__global__ __launch_bounds__(256) void combine_kernel(
    const float2* __restrict__ part, float* __restrict__ out)
{
    int wid = (blockIdx.x * 256 + threadIdx.x) >> 6;  // (b,q)
    int lane = threadIdx.x & 63;
    const float2* base = part + (size_t)wid * 64;     // 16 h x 4 ks
    float2 p = base[lane];                            // h=lane>>2, ks=lane&3
    p.x += __shfl_xor(p.x, 1); p.y += __shfl_xor(p.y, 1);
    p.x += __shfl_xor(p.x, 2); p.y += __shfl_xor(p.y, 2);
    float v = p.x / p.y;                              // per-h value, replicated x4
    for (int m = 4; m <= 32; m <<= 1) v += __shfl_xor(v, m);  // 16 distinct h, once each
    if (lane == 0) out[wid] = v;
}

extern "C" void kernel_launch(void* const* d_in, const int* in_sizes, int n_in,
                              void* d_out, int out_size, void* d_ws, size_t ws_size,
                              hipStream_t stream)
{
    const float* hs  = (const float*)d_in[0];
    const int* mask  = (const int*)d_in[1];
    const float* wq  = (const float*)d_in[2];
    const float* wk  = (const float*)d_in[3];
    const float* wv  = (const float*)d_in[4];
    const float* wo  = (const float*)d_in[5];

    char* ws = (char*)d_ws;
    unsigned short* hs_bf = (unsigned short*)ws;               // 8,388,608 B
    unsigned short* wT    = (unsigned short*)(ws + 8388608);   // 2,883,584 B
    unsigned short* Qp    = (unsigned short*)(ws + 11272192);  // 8,388,608 B
    unsigned short* Kp    = (unsigned short*)(ws + 19660800);  // 2,097,152 B
    float* vproj          = (float*)(ws + 21757952);           //   262,144 B
    float2* part          = (float2*)(ws + 22020096);          // 2,097,152 B

    prep_kernel<<<4928, 256, 0, stream>>>(hs, wq, wk, wv, wo, hs_bf, wT);
    gemm_kernel<<<dim3(11, 64), 256, 0, stream>>>(hs_bf, wT, Qp, Kp, vproj);
    attn_kernel<<<dim3(32, 8, 4), 256, 0, stream>>>(Qp, Kp, vproj, mask, part);
    combine_kernel<<<1024, 256, 0, stream>>>(part, (float*)d_out);
}

// Round 6
// 153.565 us; speedup vs baseline: 1.0512x; 1.0512x over previous
//
#include <hip/hip_runtime.h>
#include <stdint.h>

// CoEncoderDynamicAttention: B=2,S=2048,H=1024,NH=16,NKV=4,HD=64, out=(B,S,1)
// out[b,q] = sum_h (sum_k e_{hqk} * vproj[b,h,k]) / (sum_k e_{hqk})
// vproj = hs @ (wv folded with wo)  -> attn@V GEMM eliminated.
// Q' = hs@wq * (log2e/8)  -> weight = exp2(Q'.K).
// Mask folded as MFMA accumulator-init bias (0 / -30000) -> exp2 gives exact 0,
// so vproj needs NO masking (e=0 kills masked terms in num).

typedef __bf16 bf16x8 __attribute__((ext_vector_type(8)));
typedef float f32x4 __attribute__((ext_vector_type(4)));

__device__ inline unsigned short f2bf(float f) {
    unsigned int u = __builtin_bit_cast(unsigned int, f);
    u += 0x7fff + ((u >> 16) & 1);   // RNE
    return (unsigned short)(u >> 16);
}
__device__ inline bf16x8 ldfrag(const unsigned short* p) {
    uint4 v = *(const uint4*)p;
    return __builtin_bit_cast(bf16x8, v);
}
__device__ inline void gl2lds16(const unsigned short* g, unsigned short* l) {
    __builtin_amdgcn_global_load_lds(
        (const __attribute__((address_space(1))) void*)g,
        (__attribute__((address_space(3))) void*)l, 16, 0, 0);
}

#define SCALE_Q 0.18033688011112042f   // log2(e)/8

// ---------------- prep: hs->bf16; wT = [wq^T*s | wk^T | wvo^T | zeros]; biasf = mask?0:-30000
__global__ __launch_bounds__(256) void prep_kernel(
    const float* __restrict__ hs, const float* __restrict__ wq,
    const float* __restrict__ wk, const float* __restrict__ wv,
    const float* __restrict__ wo, const int* __restrict__ mask,
    unsigned short* __restrict__ hs_bf, unsigned short* __restrict__ wT,
    float* __restrict__ biasf)
{
    int bid = blockIdx.x, tid = threadIdx.x;
    if (bid < 4096) {
        int u = bid * 256 + tid;
        float4 v = ((const float4*)hs)[u];
        ushort4 o;
        o.x = f2bf(v.x); o.y = f2bf(v.y); o.z = f2bf(v.z); o.w = f2bf(v.w);
        ((ushort4*)hs_bf)[u] = o;
    } else if (bid < 4416) {
        __shared__ float tile[64 * 65];
        int t = bid - 4096;
        int ntile = t / 16, ctile = t % 16;
        int nb = ntile * 64, cb = ctile * 64;
        int tx = tid & 63, ty = tid >> 6;
        for (int i = 0; i < 16; i++) {
            int cl = i * 4 + ty;
            int n = nb + tx;
            float v = (n < 1024) ? wq[(cb + cl) * 1024 + n] * SCALE_Q
                                 : wk[(cb + cl) * 256 + (n - 1024)];
            tile[cl * 65 + tx] = v;
        }
        __syncthreads();
        for (int i = 0; i < 16; i++) {
            int nl = i * 4 + ty;
            wT[(nb + nl) * 1024 + cb + tx] = f2bf(tile[tx * 65 + nl]);
        }
    } else if (bid < 4928) {
        int u = (bid - 4416) * 256 + tid;
        int n2 = u >> 10, c = u & 1023;
        if (n2 < 16) {
            int h = n2, kv = h >> 2;
            const float* wvr = wv + c * 256 + kv * 64;
            const float* wor = wo + h * 64;
            float s = 0.f;
            #pragma unroll 8
            for (int d = 0; d < 64; d++) s += wvr[d] * wor[d];
            wT[(1280 + n2) * 1024 + c] = f2bf(s);
        } else {
            wT[(1280 + n2) * 1024 + c] = 0;
        }
    } else {
        int u = (bid - 4928) * 256 + tid;   // 4096 mask ints
        biasf[u] = mask[u] ? 0.f : -30000.f;
    }
}

// ---------------- gemm v2: 128(m=weight-col) x 64(r) tiles -> grid 11x64 = 704 blocks.
// D[n][r] = sum_c wT[n][c]*hs_bf[r][c]. n-tiles: 0..7 Q' bf16, 8..9 K bf16, 10 vproj f32.
__global__ __launch_bounds__(256) void gemm_kernel(
    const unsigned short* __restrict__ hs_bf, const unsigned short* __restrict__ wT,
    unsigned short* __restrict__ Qp, unsigned short* __restrict__ Kp,
    float* __restrict__ vproj)
{
    __shared__ __align__(16) unsigned short Al[128 * 32];
    __shared__ __align__(16) unsigned short Bl[64 * 32];
    int nt = blockIdx.x, rt = blockIdx.y;
    int tid = threadIdx.x;
    int lane = tid & 63, w = tid >> 6;
    int l15 = lane & 15, quad = lane >> 4;
    int wm = (w >> 1) * 64, wn = (w & 1) * 32;

    f32x4 acc[4][2];
    const f32x4 zero = {0.f, 0.f, 0.f, 0.f};
    for (int i = 0; i < 4; i++) for (int j = 0; j < 2; j++) acc[i][j] = zero;

    int arow = nt * 128, rrow = rt * 64;
    int scol = (lane & 3) * 8;
    const unsigned short* ga = wT + (size_t)(arow + w * 32 + (lane >> 2)) * 1024 + scol;
    const unsigned short* gb = hs_bf + (size_t)(rrow + w * 16 + (lane >> 2)) * 1024 + scol;
    unsigned short* la = Al + (w * 32) * 32;
    unsigned short* lb = Bl + (w * 16) * 32;

    for (int kk = 0; kk < 32; kk++) {
        gl2lds16(ga,             la);
        gl2lds16(ga + 16 * 1024, la + 16 * 32);
        gl2lds16(gb,             lb);
        ga += 32; gb += 32;
        __syncthreads();
        bf16x8 af[4], bfr[2];
        for (int i = 0; i < 4; i++)
            af[i]  = ldfrag(Al + (wm + i * 16 + l15) * 32 + quad * 8);
        for (int j = 0; j < 2; j++)
            bfr[j] = ldfrag(Bl + (wn + j * 16 + l15) * 32 + quad * 8);
        for (int i = 0; i < 4; i++)
            for (int j = 0; j < 2; j++)
                acc[i][j] = __builtin_amdgcn_mfma_f32_16x16x32_bf16(af[i], bfr[j], acc[i][j], 0, 0, 0);
        __syncthreads();
    }

    for (int i = 0; i < 4; i++) {
        for (int j = 0; j < 2; j++) {
            int nw = nt * 128 + wm + i * 16 + quad * 4;
            int r  = rt * 64 + wn + j * 16 + l15;
            if (nt < 8) {
                ushort4 o;
                o.x = f2bf(acc[i][j][0]); o.y = f2bf(acc[i][j][1]);
                o.z = f2bf(acc[i][j][2]); o.w = f2bf(acc[i][j][3]);
                *(ushort4*)(Qp + (size_t)r * 1024 + nw) = o;
            } else if (nt < 10) {
                ushort4 o;
                o.x = f2bf(acc[i][j][0]); o.y = f2bf(acc[i][j][1]);
                o.z = f2bf(acc[i][j][2]); o.w = f2bf(acc[i][j][3]);
                *(ushort4*)(Kp + (size_t)r * 256 + (nw - 1024)) = o;
            } else {
                for (int rg = 0; rg < 4; rg++) {
                    int h = nw + rg - 1280;
                    if (h < 16)
                        vproj[((size_t)(r >> 11) * 16 + h) * 2048 + (r & 2047)] = acc[i][j][rg];
                }
            }
        }
    }
}

// ---------------- attention v4: LDS-free, barrier-free. block=(b,kv,qt64,ks512),
// wave w -> h=kv*4+w (4 waves share K cache lines). Per t8: 2 K-frag loads (one
// 128B line per k-row), broadcast vpm4/bias4 loads, 4 independent MFMA->exp2 chains.
__global__ __launch_bounds__(256, 4) void attn_kernel(
    const unsigned short* __restrict__ Qp, const unsigned short* __restrict__ Kp,
    const float* __restrict__ vproj, const float* __restrict__ biasf,
    float2* __restrict__ part)
{
    int qt = blockIdx.x;                       // 0..31
    int b = blockIdx.y >> 2, kv = blockIdx.y & 3;
    int ks = blockIdx.z;                       // 0..3 (512 k each)
    int tid = threadIdx.x, lane = tid & 63, w = tid >> 6;
    int l15 = lane & 15, quad = lane >> 4;
    int h = kv * 4 + w;
    int qrow0 = qt * 64;

    // Q fragments: B-operand layout B[n=q (l15)][k=d]
    bf16x8 qf[4][2];
    for (int qs = 0; qs < 4; qs++) {
        const unsigned short* qp =
            Qp + (size_t)(b * 2048 + qrow0 + qs * 16 + l15) * 1024 + h * 64 + quad * 8;
        qf[qs][0] = ldfrag(qp);
        qf[qs][1] = ldfrag(qp + 32);
    }

    // A-operand K: lane reads row (t8*16+l15), d-chunk quad*8 (a0: d 0..31, a1: d 32..63)
    const unsigned short* kp =
        Kp + (size_t)(b * 2048 + ks * 512 + l15) * 256 + kv * 64 + quad * 8;
    const float* vp = vproj + ((size_t)b * 16 + h) * 2048 + ks * 512 + quad * 4;
    const float* bp = biasf + b * 2048 + ks * 512 + quad * 4;

    float num[4] = {0.f, 0.f, 0.f, 0.f}, den[4] = {0.f, 0.f, 0.f, 0.f};
    #pragma unroll 2
    for (int t8 = 0; t8 < 32; t8++) {
        bf16x8 a0 = ldfrag(kp);
        bf16x8 a1 = ldfrag(kp + 32);
        f32x4 vpm4 = *(const f32x4*)vp;
        f32x4 c4   = *(const f32x4*)bp;     // mask bias per k-row
        kp += 16 * 256; vp += 16; bp += 16;
        for (int qs = 0; qs < 4; qs++) {
            f32x4 d = __builtin_amdgcn_mfma_f32_16x16x32_bf16(a0, qf[qs][0], c4, 0, 0, 0);
            d = __builtin_amdgcn_mfma_f32_16x16x32_bf16(a1, qf[qs][1], d, 0, 0, 0);
            for (int r = 0; r < 4; r++) {
                float e = __builtin_amdgcn_exp2f(d[r]);   // exact 0 for masked rows
                num[qs] += e * vpm4[r];
                den[qs] += e;
            }
        }
    }
    for (int qs = 0; qs < 4; qs++) {
        float n = num[qs], dd = den[qs];
        n += __shfl_xor(n, 16);  n += __shfl_xor(n, 32);
        dd += __shfl_xor(dd, 16); dd += __shfl_xor(dd, 32);
        if (quad == 0) {
            int q = qrow0 + qs * 16 + l15;
            part[((size_t)(b * 2048 + q) * 16 + h) * 4 + ks] = make_float2(n, dd);
        }
    }
}

// ---------------- combine: out[b,q] = sum_h (sum_ks num)/(sum_ks den); one wave per (b,q)
__global__ __launch_bounds__(256) void combine_kernel(
    const float2* __restrict__ part, float* __restrict__ out)
{
    int wid = (blockIdx.x * 256 + threadIdx.x) >> 6;  // (b,q)
    int lane = threadIdx.x & 63;
    const float2* base = part + (size_t)wid * 64;     // 16 h x 4 ks
    float2 p = base[lane];                            // h=lane>>2, ks=lane&3
    p.x += __shfl_xor(p.x, 1); p.y += __shfl_xor(p.y, 1);
    p.x += __shfl_xor(p.x, 2); p.y += __shfl_xor(p.y, 2);
    float v = p.x / p.y;                              // per-h value, replicated x4
    for (int m = 4; m <= 32; m <<= 1) v += __shfl_xor(v, m);  // 16 distinct h, once each
    if (lane == 0) out[wid] = v;
}

extern "C" void kernel_launch(void* const* d_in, const int* in_sizes, int n_in,
                              void* d_out, int out_size, void* d_ws, size_t ws_size,
                              hipStream_t stream)
{
    const float* hs  = (const float*)d_in[0];
    const int* mask  = (const int*)d_in[1];
    const float* wq  = (const float*)d_in[2];
    const float* wk  = (const float*)d_in[3];
    const float* wv  = (const float*)d_in[4];
    const float* wo  = (const float*)d_in[5];

    char* ws = (char*)d_ws;
    unsigned short* hs_bf = (unsigned short*)ws;               // 8,388,608 B
    unsigned short* wT    = (unsigned short*)(ws + 8388608);   // 2,883,584 B
    unsigned short* Qp    = (unsigned short*)(ws + 11272192);  // 8,388,608 B
    unsigned short* Kp    = (unsigned short*)(ws + 19660800);  // 2,097,152 B
    float* vproj          = (float*)(ws + 21757952);           //   262,144 B
    float2* part          = (float2*)(ws + 22020096);          // 2,097,152 B
    float* biasf          = (float*)(ws + 24117248);           //    16,384 B

    prep_kernel<<<4944, 256, 0, stream>>>(hs, wq, wk, wv, wo, mask, hs_bf, wT, biasf);
    gemm_kernel<<<dim3(11, 64), 256, 0, stream>>>(hs_bf, wT, Qp, Kp, vproj);
    attn_kernel<<<dim3(32, 8, 4), 256, 0, stream>>>(Qp, Kp, vproj, biasf, part);
    combine_kernel<<<1024, 256, 0, stream>>>(part, (float*)d_out);
}